// Round 4
// baseline (883.610 us; speedup 1.0000x reference)
//
#include <hip/hip_runtime.h>
#include <hip/hip_bf16.h>
#include <stdint.h>

#define E_DIM 128
#define L_SEQ 512
#define B_SZ  128

typedef _Float16 h2 __attribute__((ext_vector_type(2)));
typedef _Float16 f16x8 __attribute__((ext_vector_type(8)));
typedef float f32x4 __attribute__((ext_vector_type(4)));

// ---------------- workspace layout (bytes) ----------------
constexpr size_t SZ_W12 = 512 * 128 * 4;
constexpr size_t SZ_TQ  = 10001 * 128 * 4;
constexpr size_t SZ_TC  = 301 * 128 * 4;
constexpr size_t SZ_TS  = 200 * 128 * 4;
constexpr size_t SZ_TA  = 20002 * 128 * 4;

constexpr size_t OFF_W12  = 0;
constexpr size_t OFF_W13  = OFF_W12 + SZ_W12;
constexpr size_t OFF_BV2  = OFF_W13 + SZ_W12;
constexpr size_t OFF_BV3  = OFF_BV2 + 512;
constexpr size_t OFF_TQ2  = OFF_BV3 + 512;
constexpr size_t OFF_TQ3  = OFF_TQ2 + SZ_TQ;
constexpr size_t OFF_TC2  = OFF_TQ3 + SZ_TQ;
constexpr size_t OFF_TC3  = OFF_TC2 + SZ_TC;
constexpr size_t OFF_TSD2 = OFF_TC3 + SZ_TC;
constexpr size_t OFF_TSD3 = OFF_TSD2 + SZ_TS;
constexpr size_t OFF_TSD6 = OFF_TSD3 + SZ_TS;
constexpr size_t OFF_TQD2 = OFF_TSD6 + SZ_TS;
constexpr size_t OFF_TQD3 = OFF_TQD2 + SZ_TS;
constexpr size_t OFF_TQD6 = OFF_TQD3 + SZ_TS;
constexpr size_t OFF_TA4  = OFF_TQD6 + SZ_TS;
constexpr size_t OFF_TA5  = OFF_TA4 + SZ_TA;
constexpr size_t OFF_TA6  = OFF_TA5 + SZ_TA;
constexpr size_t OFF_K    = OFF_TA6 + SZ_TA;      // 33.5 MB

// ---------------- helpers ----------------
__device__ __forceinline__ float fdot2f(unsigned int a, unsigned int b, float c) {
#if __has_builtin(__builtin_amdgcn_fdot2)
  return __builtin_amdgcn_fdot2(__builtin_bit_cast(h2, a), __builtin_bit_cast(h2, b), c, false);
#else
  h2 x = __builtin_bit_cast(h2, a), y = __builtin_bit_cast(h2, b);
  return c + (float)x[0] * (float)y[0] + (float)x[1] * (float)y[1];
#endif
}

__device__ __forceinline__ unsigned int packh2(float a, float b) {
  h2 v; v[0] = (_Float16)a; v[1] = (_Float16)b;
  return __builtin_bit_cast(unsigned int, v);
}

__device__ __forceinline__ float fsig(float x) {
  float t = __builtin_amdgcn_exp2f(-1.4426950408889634f * x);
  return __builtin_amdgcn_rcpf(1.0f + t);
}
__device__ __forceinline__ float ftanh(float x) {
  float t = __builtin_amdgcn_exp2f(2.8853900817779268f * x);
  return 1.0f - 2.0f * __builtin_amdgcn_rcpf(t + 1.0f);
}

// LDS-only barrier: no vmcnt drain -> global prefetch stays in flight
#define BARRIER_RAW() asm volatile("s_waitcnt lgkmcnt(0)\n\ts_barrier" ::: "memory")

// ---------------- prep A: W12 = W1@W2, W13 = W1@W3 (2 rows/block) ----------------
__global__ __launch_bounds__(256, 2) void prepA_kernel(
    const float* __restrict__ W1, const float* __restrict__ W2, const float* __restrict__ W3,
    const float* __restrict__ b1, const float* __restrict__ b2, const float* __restrict__ b3,
    char* __restrict__ ws) {
  float* W12 = (float*)(ws + OFF_W12);
  float* W13 = (float*)(ws + OFF_W13);
  float* bv2 = (float*)(ws + OFF_BV2);
  float* bv3 = (float*)(ws + OFF_BV3);
  const int blk = blockIdx.x, tid = threadIdx.x;
  if (blk < 512) {
    const int m = blk >> 8;        // 0 -> W12, 1 -> W13
    const int rp = blk & 255;      // row pair
    const float* M = m ? W3 : W2;
    float* dst = m ? W13 : W12;
    const int rr = tid >> 7, j = tid & 127;
    const int r = rp * 2 + rr;
    __shared__ float rowL[2][128];
    rowL[rr][j] = W1[r * 128 + j];
    __syncthreads();
    float acc = 0.0f;
#pragma unroll 8
    for (int t = 0; t < 128; t++) acc += rowL[rr][t] * M[t * 128 + j];
    dst[r * 128 + j] = acc;
  } else if (tid < 128) {
    float a2 = b2[tid], a3 = b3[tid];
    for (int t = 0; t < 128; t++) {
      float bb = b1[t];
      a2 += bb * W2[t * 128 + tid];
      a3 += bb * W3[t * 128 + tid];
    }
    bv2[tid] = a2;
    bv3[tid] = a3;
  }
}

// ---------------- table transforms: one 128-col segment per block, MFMA f16 ----------------
// grid = 647: q2(79) q3(79) c2(3) c3(3) sd2(2) sd3(2) sd6(2) qd2(2) qd3(2) qd6(2)
//             a4(157) a5(157) a6(157)
__global__ __launch_bounds__(256, 2) void gemm_tab1_kernel(
    const float* __restrict__ q_tab, const float* __restrict__ c_tab,
    const float* __restrict__ sd_tab, const float* __restrict__ qd_tab,
    const float* __restrict__ a_tab,
    const float* __restrict__ W4, const float* __restrict__ W5, const float* __restrict__ W6,
    const float* __restrict__ b4, const float* __restrict__ b5, const float* __restrict__ b6,
    char* __restrict__ ws) {
  __shared__ _Float16 BT[128][136];   // B^T [col][k], padded
  __shared__ _Float16 At[32][136];    // A chunk [row][k], padded
  __shared__ float biasL[128];

  const float* W12 = (const float*)(ws + OFF_W12);
  const float* W13 = (const float*)(ws + OFF_W13);
  const float* bv2f = (const float*)(ws + OFF_BV2);
  const float* bv3f = (const float*)(ws + OFF_BV3);

  const int bid = blockIdx.x, tid = threadIdx.x;
  const int wv = tid >> 6, ln = tid & 63;

  int task, rb;
  if      (bid < 79)  { task = 0;  rb = bid; }
  else if (bid < 158) { task = 1;  rb = bid - 79; }
  else if (bid < 161) { task = 2;  rb = bid - 158; }
  else if (bid < 164) { task = 3;  rb = bid - 161; }
  else if (bid < 166) { task = 4;  rb = bid - 164; }
  else if (bid < 168) { task = 5;  rb = bid - 166; }
  else if (bid < 170) { task = 6;  rb = bid - 168; }
  else if (bid < 172) { task = 7;  rb = bid - 170; }
  else if (bid < 174) { task = 8;  rb = bid - 172; }
  else if (bid < 176) { task = 9;  rb = bid - 174; }
  else if (bid < 333) { task = 10; rb = bid - 176; }
  else if (bid < 490) { task = 11; rb = bid - 333; }
  else                { task = 12; rb = bid - 490; }

  const float* src; int rows; const float* Bsrc; const float* bias; float* dst;
  switch (task) {
    case 0:  src = q_tab;  rows = 10001; Bsrc = W12;            bias = bv2f;   dst = (float*)(ws + OFF_TQ2);  break;
    case 1:  src = q_tab;  rows = 10001; Bsrc = W13;            bias = bv3f;   dst = (float*)(ws + OFF_TQ3);  break;
    case 2:  src = c_tab;  rows = 301;   Bsrc = W12 + 128*128;  bias = nullptr; dst = (float*)(ws + OFF_TC2);  break;
    case 3:  src = c_tab;  rows = 301;   Bsrc = W13 + 128*128;  bias = nullptr; dst = (float*)(ws + OFF_TC3);  break;
    case 4:  src = sd_tab; rows = 200;   Bsrc = W12 + 256*128;  bias = nullptr; dst = (float*)(ws + OFF_TSD2); break;
    case 5:  src = sd_tab; rows = 200;   Bsrc = W13 + 256*128;  bias = nullptr; dst = (float*)(ws + OFF_TSD3); break;
    case 6:  src = sd_tab; rows = 200;   Bsrc = W6  + 256*128;  bias = nullptr; dst = (float*)(ws + OFF_TSD6); break;
    case 7:  src = qd_tab; rows = 200;   Bsrc = W12 + 384*128;  bias = nullptr; dst = (float*)(ws + OFF_TQD2); break;
    case 8:  src = qd_tab; rows = 200;   Bsrc = W13 + 384*128;  bias = nullptr; dst = (float*)(ws + OFF_TQD3); break;
    case 9:  src = qd_tab; rows = 200;   Bsrc = W6  + 384*128;  bias = nullptr; dst = (float*)(ws + OFF_TQD6); break;
    case 10: src = a_tab;  rows = 20002; Bsrc = W4  + 128*128;  bias = b4;     dst = (float*)(ws + OFF_TA4);  break;
    case 11: src = a_tab;  rows = 20002; Bsrc = W5  + 128*128;  bias = b5;     dst = (float*)(ws + OFF_TA5);  break;
    default: src = a_tab;  rows = 20002; Bsrc = W6  + 128*128;  bias = b6;     dst = (float*)(ws + OFF_TA6);  break;
  }

  // ---- stage B^T (f16) : coalesced float4 reads, transposed f16 LDS writes ----
#pragma unroll
  for (int r = 0; r < 8; r++) {
    const int k = (tid >> 4) + r * 16;
    const int j0 = (tid & 15) * 8;
    float4 v0 = *(const float4*)(Bsrc + k * 128 + j0);
    float4 v1 = *(const float4*)(Bsrc + k * 128 + j0 + 4);
    BT[j0 + 0][k] = (_Float16)v0.x; BT[j0 + 1][k] = (_Float16)v0.y;
    BT[j0 + 2][k] = (_Float16)v0.z; BT[j0 + 3][k] = (_Float16)v0.w;
    BT[j0 + 4][k] = (_Float16)v1.x; BT[j0 + 5][k] = (_Float16)v1.y;
    BT[j0 + 6][k] = (_Float16)v1.z; BT[j0 + 7][k] = (_Float16)v1.w;
  }
  if (tid < 128) biasL[tid] = bias ? bias[tid] : 0.0f;
  __syncthreads();

  // ---- hoist B fragments ----
  f16x8 bfr[2][4];
#pragma unroll
  for (int ct = 0; ct < 2; ct++)
#pragma unroll
    for (int kt = 0; kt < 4; kt++) {
      const int col = wv * 32 + ct * 16 + (ln & 15);
      const int k = kt * 32 + (ln >> 4) * 8;
      bfr[ct][kt] = *(const f16x8*)&BT[col][k];
    }
  float bvl[2] = { biasL[wv * 32 + (ln & 15)], biasL[wv * 32 + 16 + (ln & 15)] };

  const int row_base = rb * 128;
  for (int ch = 0; ch < 4; ch++) {
    const int row0 = row_base + ch * 32;
    {
      const int r = tid >> 3, cb = (tid & 7) * 16;
      int sr = row0 + r; if (sr >= rows) sr = rows - 1;
      const float4* s4 = (const float4*)(src + (size_t)sr * 128 + cb);
      float4 v0 = s4[0], v1 = s4[1], v2 = s4[2], v3 = s4[3];
      f16x8 lo, hi;
      lo[0] = (_Float16)v0.x; lo[1] = (_Float16)v0.y; lo[2] = (_Float16)v0.z; lo[3] = (_Float16)v0.w;
      lo[4] = (_Float16)v1.x; lo[5] = (_Float16)v1.y; lo[6] = (_Float16)v1.z; lo[7] = (_Float16)v1.w;
      hi[0] = (_Float16)v2.x; hi[1] = (_Float16)v2.y; hi[2] = (_Float16)v2.z; hi[3] = (_Float16)v2.w;
      hi[4] = (_Float16)v3.x; hi[5] = (_Float16)v3.y; hi[6] = (_Float16)v3.z; hi[7] = (_Float16)v3.w;
      *(f16x8*)&At[r][cb] = lo;
      *(f16x8*)&At[r][cb + 8] = hi;
    }
    __syncthreads();
    f16x8 af[2][4];
#pragma unroll
    for (int rt = 0; rt < 2; rt++)
#pragma unroll
      for (int kt = 0; kt < 4; kt++) {
        const int row = rt * 16 + (ln & 15);
        const int k = kt * 32 + (ln >> 4) * 8;
        af[rt][kt] = *(const f16x8*)&At[row][k];
      }
    f32x4 acc[2][2];
#pragma unroll
    for (int rt = 0; rt < 2; rt++)
#pragma unroll
      for (int ct = 0; ct < 2; ct++) acc[rt][ct] = (f32x4){0.f, 0.f, 0.f, 0.f};
#pragma unroll
    for (int kt = 0; kt < 4; kt++)
#pragma unroll
      for (int ct = 0; ct < 2; ct++)
#pragma unroll
        for (int rt = 0; rt < 2; rt++)
          acc[rt][ct] = __builtin_amdgcn_mfma_f32_16x16x32_f16(af[rt][kt], bfr[ct][kt], acc[rt][ct], 0, 0, 0);
#pragma unroll
    for (int ct = 0; ct < 2; ct++) {
      const int col = wv * 32 + ct * 16 + (ln & 15);
      const float bv = bvl[ct];
#pragma unroll
      for (int rt = 0; rt < 2; rt++)
#pragma unroll
        for (int e = 0; e < 4; e++) {
          const int row = row0 + rt * 16 + (ln >> 4) * 4 + e;
          if (row < rows) dst[(size_t)row * 128 + col] = acc[rt][ct][e] + bv;
        }
    }
    __syncthreads();
  }
}

// ---------------- scan: 2 batches/block (512 thr), split-K inside the wave ----------------
// group g = tid>>8 handles batch 2*bid+g; within group: lane l of wave w:
// j = 32*w + (l&31), h = l>>5. Half-combine via shfl_xor(32); 2 raw barriers/step.

#define PREFETCH(S, P) do {                                                   \
    int _s = (S);                                                             \
    int _qi = idxb[g][0][_s], _ci = idxb[g][1][_s], _si = idxb[g][2][_s];     \
    int _di = idxb[g][3][_s], _ai = idxb[g][4][_s];                           \
    P##q2 = Tq2[_qi * 128 + j]; P##q3 = Tq3[_qi * 128 + j];                   \
    P##c2 = Tc2[_ci * 128 + j]; P##c3 = Tc3[_ci * 128 + j];                   \
    P##s2 = Ts2[_si * 128 + j]; P##s3 = Ts3[_si * 128 + j];                   \
    P##s6 = Ts6[_si * 128 + j];                                               \
    P##d2 = Td2[_di * 128 + j]; P##d3 = Td3[_di * 128 + j];                   \
    P##d6 = Td6[_di * 128 + j];                                               \
    P##a4 = Ta4[_ai * 128 + j]; P##a5 = Ta5[_ai * 128 + j];                   \
    P##a6 = Ta6[_ai * 128 + j];                                               \
  } while (0)

#define SCAN_STEP(P, S2, L) do {                                              \
    float u2a = 0.f, u2b = 0.f, u3a = 0.f, u3b = 0.f, u6a = 0.f, u6b = 0.f;   \
    {                                                                         \
      const uint4* kp4 = ((const uint4*)kpair[g]) + 8 * h;                    \
      _Pragma("unroll")                                                       \
      for (int i = 0; i < 8; i++) {                                           \
        uint4 kv = kp4[i];                                                    \
        u2a = fdot2f(kv.x, w2h[4 * i + 0], u2a);                              \
        u3a = fdot2f(kv.x, w3h[4 * i + 0], u3a);                              \
        u6a = fdot2f(kv.x, w6h[4 * i + 0], u6a);                              \
        u2b = fdot2f(kv.y, w2h[4 * i + 1], u2b);                              \
        u3b = fdot2f(kv.y, w3h[4 * i + 1], u3b);                              \
        u6b = fdot2f(kv.y, w6h[4 * i + 1], u6b);                              \
        u2a = fdot2f(kv.z, w2h[4 * i + 2], u2a);                              \
        u3a = fdot2f(kv.z, w3h[4 * i + 2], u3a);                              \
        u6a = fdot2f(kv.z, w6h[4 * i + 2], u6a);                              \
        u2b = fdot2f(kv.w, w2h[4 * i + 3], u2b);                              \
        u3b = fdot2f(kv.w, w3h[4 * i + 3], u3b);                              \
        u6b = fdot2f(kv.w, w6h[4 * i + 3], u6b);                              \
      }                                                                       \
    }                                                                         \
    float U2p = u2a + u2b, U3p = u3a + u3b, U6p = u6a + u6b;                  \
    U2p += __shfl_xor(U2p, 32);                                               \
    U3p += __shfl_xor(U3p, 32);                                               \
    U6p += __shfl_xor(U6p, 32);                                               \
    float U2 = (P##q2 + P##c2 + P##s2 + P##d2) - U2p;                         \
    float U3 = (P##q3 + P##c3 + P##s3 + P##d3) - U3p;                         \
    float U6 = (P##a6 + P##s6 + P##d6) + U6p;                                 \
    float sdft = fsig(U2) * ftanh(U3);                                        \
    float g_ = fsig(U6);                                                      \
    if (!h) ((_Float16*)sdfp[g])[j] = (_Float16)sdft;                         \
    BARRIER_RAW(); /* B1: sdft broadcast */                                   \
    float u4a = 0.f, u4b = 0.f, u5a = 0.f, u5b = 0.f;                         \
    {                                                                         \
      const uint4* sp4 = ((const uint4*)sdfp[g]) + 8 * h;                     \
      _Pragma("unroll")                                                       \
      for (int i = 0; i < 8; i++) {                                           \
        uint4 sv = sp4[i];                                                    \
        u4a = fdot2f(sv.x, w4h[4 * i + 0], u4a);                              \
        u5a = fdot2f(sv.x, w5h[4 * i + 0], u5a);                              \
        u4b = fdot2f(sv.y, w4h[4 * i + 1], u4b);                              \
        u5b = fdot2f(sv.y, w5h[4 * i + 1], u5b);                              \
        u4a = fdot2f(sv.z, w4h[4 * i + 2], u4a);                              \
        u5a = fdot2f(sv.z, w5h[4 * i + 2], u5a);                              \
        u4b = fdot2f(sv.w, w4h[4 * i + 3], u4b);                              \
        u5b = fdot2f(sv.w, w5h[4 * i + 3], u5b);                              \
      }                                                                       \
    }                                                                         \
    float U4p = u4a + u4b, U5p = u5a + u5b;                                   \
    U4p += __shfl_xor(U4p, 32);                                               \
    U5p += __shfl_xor(U5p, 32);                                               \
    float pk = fsig(U4p + P##a4) * ftanh(U5p + P##a5);                        \
    k = g_ * k + (1.0f - g_) * pk;                                            \
    if (h) ((_Float16*)kpair[g])[j] = (_Float16)k;                            \
    if (!h) Kout[((size_t)(base + (L))) * 128 + j] = k;                       \
    PREFETCH(S2, P);                                                          \
    BARRIER_RAW(); /* B2: k broadcast */                                      \
  } while (0)

__global__ __launch_bounds__(512, 2) void scan_kernel(
    const int* __restrict__ q, const int* __restrict__ c, const int* __restrict__ sd,
    const int* __restrict__ qd, const int* __restrict__ a,
    const float* __restrict__ knowledge,
    const float* __restrict__ W2, const float* __restrict__ W3, const float* __restrict__ W4,
    const float* __restrict__ W5, const float* __restrict__ W6,
    char* __restrict__ ws) {
  const int tid = threadIdx.x;
  const int g = tid >> 8;            // batch group within block
  const int t256 = tid & 255;
  const int ln = tid & 63;
  const int wvl = (t256 >> 6);
  const int j = (wvl << 5) | (ln & 31);
  const int h = ln >> 5;
  const int b = (blockIdx.x << 1) | g;
  const int base = b * L_SEQ;

  const float* Tq2 = (const float*)(ws + OFF_TQ2);
  const float* Tq3 = (const float*)(ws + OFF_TQ3);
  const float* Tc2 = (const float*)(ws + OFF_TC2);
  const float* Tc3 = (const float*)(ws + OFF_TC3);
  const float* Ts2 = (const float*)(ws + OFF_TSD2);
  const float* Ts3 = (const float*)(ws + OFF_TSD3);
  const float* Ts6 = (const float*)(ws + OFF_TSD6);
  const float* Td2 = (const float*)(ws + OFF_TQD2);
  const float* Td3 = (const float*)(ws + OFF_TQD3);
  const float* Td6 = (const float*)(ws + OFF_TQD6);
  const float* Ta4 = (const float*)(ws + OFF_TA4);
  const float* Ta5 = (const float*)(ws + OFF_TA5);
  const float* Ta6 = (const float*)(ws + OFF_TA6);
  float* Kout = (float*)(ws + OFF_K);

  __shared__ int idxb[2][5][L_SEQ];                    // 20 KB
  __shared__ __align__(16) unsigned int kpair[2][64];
  __shared__ __align__(16) unsigned int sdfp[2][64];

  idxb[g][0][t256] = q[base + t256];  idxb[g][0][t256 + 256] = q[base + t256 + 256];
  idxb[g][1][t256] = c[base + t256];  idxb[g][1][t256 + 256] = c[base + t256 + 256];
  idxb[g][2][t256] = sd[base + t256]; idxb[g][2][t256 + 256] = sd[base + t256 + 256];
  idxb[g][3][t256] = qd[base + t256]; idxb[g][3][t256 + 256] = qd[base + t256 + 256];
  idxb[g][4][t256] = a[base + t256];  idxb[g][4][t256 + 256] = a[base + t256 + 256];

  // weight half-columns (K rows [64h, 64h+64)) as f16 pairs: 32 regs/matrix
  unsigned int w2h[32], w3h[32], w6h[32], w4h[32], w5h[32];
  const int t0 = h * 64;
#pragma unroll
  for (int p = 0; p < 32; p++) {
    w2h[p] = packh2(W2[(t0 + 2 * p) * 128 + j], W2[(t0 + 2 * p + 1) * 128 + j]);
    w3h[p] = packh2(W3[(t0 + 2 * p) * 128 + j], W3[(t0 + 2 * p + 1) * 128 + j]);
    w6h[p] = packh2(W6[(t0 + 2 * p) * 128 + j], W6[(t0 + 2 * p + 1) * 128 + j]);
    w4h[p] = packh2(W4[(t0 + 2 * p) * 128 + j], W4[(t0 + 2 * p + 1) * 128 + j]);
    w5h[p] = packh2(W5[(t0 + 2 * p) * 128 + j], W5[(t0 + 2 * p + 1) * 128 + j]);
  }

  float k = knowledge[j];
  if (h) ((_Float16*)kpair[g])[j] = (_Float16)k;
  __syncthreads();

  float gAq2, gAq3, gAc2, gAc3, gAs2, gAs3, gAs6, gAd2, gAd3, gAd6, gAa4, gAa5, gAa6;
  float gBq2, gBq3, gBc2, gBc3, gBs2, gBs3, gBs6, gBd2, gBd3, gBd6, gBa4, gBa5, gBa6;
  PREFETCH(0, gA);
  PREFETCH(1, gB);

#pragma unroll 1
  for (int m = 0; m < L_SEQ / 2; m++) {
    const int l0 = 2 * m;
    const int s2 = (l0 + 2 < L_SEQ) ? (l0 + 2) : (L_SEQ - 1);
    const int s3 = (l0 + 3 < L_SEQ) ? (l0 + 3) : (L_SEQ - 1);
    SCAN_STEP(gA, s2, l0);
    SCAN_STEP(gB, s3, l0 + 1);
  }
}

// ---------------- logits head: one row per thread, Wf broadcast from LDS ----------------
__global__ __launch_bounds__(256, 2) void logits_kernel(
    const float* __restrict__ Wf, const float* __restrict__ bf,
    const char* __restrict__ ws, float* __restrict__ out) {
  __shared__ float WfL[1280];
  __shared__ float bfL[10];
  const int tid = threadIdx.x;
  for (int i = tid; i < 1280; i += 256) WfL[i] = Wf[i];
  if (tid < 10) bfL[tid] = bf[tid];
  __syncthreads();
  const float* K = (const float*)(ws + OFF_K);
  const int nrows = B_SZ * L_SEQ;
  for (int r = blockIdx.x * 256 + tid; r < nrows; r += gridDim.x * 256) {
    const float4* kr = (const float4*)(K + (size_t)r * 128);
    float acc[10];
#pragma unroll
    for (int i = 0; i < 10; i++) acc[i] = bfL[i];
#pragma unroll
    for (int t4 = 0; t4 < 32; t4++) {
      float4 v = kr[t4];
#pragma unroll
      for (int i = 0; i < 10; i++)
        acc[i] += v.x * WfL[(4 * t4 + 0) * 10 + i] + v.y * WfL[(4 * t4 + 1) * 10 + i] +
                  v.z * WfL[(4 * t4 + 2) * 10 + i] + v.w * WfL[(4 * t4 + 3) * 10 + i];
    }
    float* o = out + (size_t)r * 10;
#pragma unroll
    for (int i = 0; i < 10; i++) o[i] = fsig(acc[i]);
  }
}

extern "C" void kernel_launch(void* const* d_in, const int* in_sizes, int n_in,
                              void* d_out, int out_size, void* d_ws, size_t ws_size,
                              hipStream_t stream) {
  const int* q  = (const int*)d_in[0];
  const int* c  = (const int*)d_in[1];
  const int* sd = (const int*)d_in[2];
  const int* qd = (const int*)d_in[3];
  const int* a  = (const int*)d_in[4];
  const float* knowledge = (const float*)d_in[9];
  const float* q_tab  = (const float*)d_in[10];
  const float* c_tab  = (const float*)d_in[11];
  const float* sd_tab = (const float*)d_in[12];
  const float* qd_tab = (const float*)d_in[13];
  const float* a_tab  = (const float*)d_in[14];
  const float* W1 = (const float*)d_in[15];
  const float* b1 = (const float*)d_in[16];
  const float* W2 = (const float*)d_in[17];
  const float* b2 = (const float*)d_in[18];
  const float* W3 = (const float*)d_in[19];
  const float* b3 = (const float*)d_in[20];
  const float* W4 = (const float*)d_in[21];
  const float* b4 = (const float*)d_in[22];
  const float* W5 = (const float*)d_in[23];
  const float* b5 = (const float*)d_in[24];
  const float* W6 = (const float*)d_in[25];
  const float* b6 = (const float*)d_in[26];
  const float* Wf = (const float*)d_in[27];
  const float* bf = (const float*)d_in[28];
  char* ws = (char*)d_ws;
  float* out = (float*)d_out;

  prepA_kernel<<<513, 256, 0, stream>>>(W1, W2, W3, b1, b2, b3, ws);
  gemm_tab1_kernel<<<647, 256, 0, stream>>>(q_tab, c_tab, sd_tab, qd_tab, a_tab,
                                            W4, W5, W6, b4, b5, b6, ws);
  scan_kernel<<<B_SZ / 2, 512, 0, stream>>>(q, c, sd, qd, a, knowledge, W2, W3, W4, W5, W6, ws);
  logits_kernel<<<256, 256, 0, stream>>>(Wf, bf, ws, out);
}